// Round 1
// baseline (1593.699 us; speedup 1.0000x reference)
//
#include <hip/hip_runtime.h>
#include <hip/hip_bf16.h>

// Problem constants
#define T_    1024
#define B_    4
#define D_    768
#define H_    12
#define HD_   64
#define FF_   3072
#define NTOK  4096     // T_*B_
#define NH_   48       // B_*H_

static const float ALPHA_ = 2.2133638394006434f; // 24^0.25

// ---------------------------------------------------------------------------
// Generic tiled fp32 GEMM: Out = X (N x K) @ W^T (M x K) + bias, with epilogue
// modes. Grid: (M/64, N/64), 256 threads.
// ---------------------------------------------------------------------------
#define MODE_PLAIN 0
#define MODE_GELU  1
#define MODE_HEAD  2

__global__ __launch_bounds__(256) void gemm_xwt(
    const float* __restrict__ X, const float* __restrict__ W,
    const float* __restrict__ bias, float* __restrict__ out,
    int K, int M, int mode, float scale) {
  __shared__ float Xs[16][64];
  __shared__ float Ws[16][64];
  int tid  = threadIdx.x;
  int row0 = blockIdx.y * 64;
  int col0 = blockIdx.x * 64;
  int tr = tid >> 4, tc = tid & 15;

  float acc[4][4];
#pragma unroll
  for (int i = 0; i < 4; i++)
#pragma unroll
    for (int j = 0; j < 4; j++) acc[i][j] = 0.f;

  int lr = tid >> 2;          // 0..63
  int lc = (tid & 3) * 4;     // 0,4,8,12
  const float* Xp = X + (size_t)(row0 + lr) * K + lc;
  const float* Wp = W + (size_t)(col0 + lr) * K + lc;

  for (int k0 = 0; k0 < K; k0 += 16) {
    float4 xv = *(const float4*)(Xp + k0);
    float4 wv = *(const float4*)(Wp + k0);
    __syncthreads();
    Xs[lc + 0][lr] = xv.x; Xs[lc + 1][lr] = xv.y;
    Xs[lc + 2][lr] = xv.z; Xs[lc + 3][lr] = xv.w;
    Ws[lc + 0][lr] = wv.x; Ws[lc + 1][lr] = wv.y;
    Ws[lc + 2][lr] = wv.z; Ws[lc + 3][lr] = wv.w;
    __syncthreads();
#pragma unroll
    for (int kk = 0; kk < 16; kk++) {
      float4 a = *(const float4*)&Xs[kk][tr * 4];
      float4 b = *(const float4*)&Ws[kk][tc * 4];
      float av[4] = {a.x, a.y, a.z, a.w};
      float bv[4] = {b.x, b.y, b.z, b.w};
#pragma unroll
      for (int i = 0; i < 4; i++)
#pragma unroll
        for (int j = 0; j < 4; j++) acc[i][j] += av[i] * bv[j];
    }
  }

  if (mode == MODE_HEAD) {
    // scatter to (b*H + h, t, hd) layout with post-bias scale
#pragma unroll
    for (int i = 0; i < 4; i++) {
      int row = row0 + tr * 4 + i;
      int t = row >> 2, bb = row & 3;
#pragma unroll
      for (int j = 0; j < 4; j++) {
        int col = col0 + tc * 4 + j;
        int h = col >> 6, hd = col & 63;
        float v = (acc[i][j] + bias[col]) * scale;
        out[(((size_t)(bb * H_ + h)) * T_ + t) * HD_ + hd] = v;
      }
    }
  } else {
#pragma unroll
    for (int i = 0; i < 4; i++) {
      int row = row0 + tr * 4 + i;
#pragma unroll
      for (int j = 0; j < 4; j++) {
        int col = col0 + tc * 4 + j;
        float v = acc[i][j] + bias[col];
        if (mode == MODE_GELU)
          v = 0.5f * v * (1.f + erff(v * 0.70710678118654752f));
        out[(size_t)row * M + col] = v;
      }
    }
  }
}

// ---------------------------------------------------------------------------
// Gate kernel: mask_scale[n][t] = ga*(gb*grep_a[h]-1)+2 from q_full = q*256
// ---------------------------------------------------------------------------
__global__ __launch_bounds__(256) void gate_kernel(
    const float* __restrict__ qh, const float* __restrict__ grep_w,
    const float* __restrict__ grep_b, const float* __restrict__ grep_a,
    float* __restrict__ msc) {
  int gid = blockIdx.x * 256 + threadIdx.x;   // n*1024 + t
  int n = gid >> 10;
  int h = n % H_;
  const float* q = qh + (size_t)gid * HD_;
  float z[8];
#pragma unroll
  for (int o = 0; o < 8; o++) z[o] = grep_b[o];
  for (int k = 0; k < 64; k++) {
    float qv = q[k] * 256.f;   // undo the 1/256 scale -> q_full
#pragma unroll
    for (int o = 0; o < 8; o++) z[o] += qv * grep_w[o * 64 + k];
  }
  float s0 = z[0] + z[1] + z[2] + z[3];
  float s1 = z[4] + z[5] + z[6] + z[7];
  float ga = 1.f / (1.f + expf(-s0));
  float gb = 1.f / (1.f + expf(-s1));
  msc[gid] = ga * (gb * grep_a[h] - 1.f) + 2.f;
}

// ---------------------------------------------------------------------------
// Flash attention (fp32). logits = 32*(q.k) + msc[n][t]*bias[n][t][s].
// Grid: (T/64, 48). 256 threads: thread = r*8+c, r in 0..31 handles rows r and
// r+32 of the 64-row tile; c in 0..7 handles s = sj*8+c and out dims c*8..c*8+7.
// ---------------------------------------------------------------------------
__global__ __launch_bounds__(256) void flash_attn(
    const float* __restrict__ Q, const float* __restrict__ Kh,
    const float* __restrict__ Vh, const float* __restrict__ bias,
    const float* __restrict__ msc, float* __restrict__ ctx) {
  __shared__ float Qs[64][68];
  __shared__ float Ks[64][68];
  __shared__ float Vs[64][68];
  int n  = blockIdx.y;
  int rb = blockIdx.x * 64;
  int tid = threadIdx.x;
  int r = tid >> 3;   // 0..31
  int c = tid & 7;    // 0..7
  int b = n / H_, h = n % H_;
  const float* Qp = Q  + (size_t)n * T_ * HD_;
  const float* Kp = Kh + (size_t)n * T_ * HD_;
  const float* Vp = Vh + (size_t)n * T_ * HD_;

  {   // load Q tile 64x64
    int qr = tid >> 2, qs = (tid & 3) * 16;
    const float4* src = (const float4*)(Qp + (size_t)(rb + qr) * HD_ + qs);
    float4* dst = (float4*)&Qs[qr][qs];
    dst[0] = src[0]; dst[1] = src[1]; dst[2] = src[2]; dst[3] = src[3];
  }

  float m0 = -1e30f, m1 = -1e30f, l0 = 0.f, l1 = 0.f;
  float O0[8], O1[8];
#pragma unroll
  for (int d = 0; d < 8; d++) { O0[d] = 0.f; O1[d] = 0.f; }
  float ms0 = msc[n * T_ + rb + r];
  float ms1 = msc[n * T_ + rb + r + 32];
  const float* br0 = bias + ((size_t)n * T_ + rb + r) * T_;
  const float* br1 = bias + ((size_t)n * T_ + rb + r + 32) * T_;

  for (int cb = 0; cb < T_; cb += 64) {
    __syncthreads();
    {   // load K,V tiles 64x64
      int kr = tid >> 2, ks = (tid & 3) * 16;
      const float4* sk = (const float4*)(Kp + (size_t)(cb + kr) * HD_ + ks);
      const float4* sv = (const float4*)(Vp + (size_t)(cb + kr) * HD_ + ks);
      float4* dk = (float4*)&Ks[kr][ks];
      float4* dv = (float4*)&Vs[kr][ks];
      dk[0] = sk[0]; dk[1] = sk[1]; dk[2] = sk[2]; dk[3] = sk[3];
      dv[0] = sv[0]; dv[1] = sv[1]; dv[2] = sv[2]; dv[3] = sv[3];
    }
    __syncthreads();

    float p0[8], p1[8];
#pragma unroll
    for (int sj = 0; sj < 8; sj++) { p0[sj] = 0.f; p1[sj] = 0.f; }
    for (int k4 = 0; k4 < 64; k4 += 4) {
      float4 qa = *(const float4*)&Qs[r][k4];
      float4 qb = *(const float4*)&Qs[r + 32][k4];
#pragma unroll
      for (int sj = 0; sj < 8; sj++) {
        int s = sj * 8 + c;
        float4 kv = *(const float4*)&Ks[s][k4];
        p0[sj] += qa.x * kv.x + qa.y * kv.y + qa.z * kv.z + qa.w * kv.w;
        p1[sj] += qb.x * kv.x + qb.y * kv.y + qb.z * kv.z + qb.w * kv.w;
      }
    }
    float tmax0 = -1e30f, tmax1 = -1e30f;
#pragma unroll
    for (int sj = 0; sj < 8; sj++) {
      int s = sj * 8 + c;
      float bv0 = br0[cb + s];
      float bv1 = br1[cb + s];
      p0[sj] = p0[sj] * 32.f + ms0 * bv0;
      p1[sj] = p1[sj] * 32.f + ms1 * bv1;
      tmax0 = fmaxf(tmax0, p0[sj]);
      tmax1 = fmaxf(tmax1, p1[sj]);
    }
#pragma unroll
    for (int off = 1; off < 8; off <<= 1) {
      tmax0 = fmaxf(tmax0, __shfl_xor(tmax0, off));
      tmax1 = fmaxf(tmax1, __shfl_xor(tmax1, off));
    }
    float mn0 = fmaxf(m0, tmax0), mn1 = fmaxf(m1, tmax1);
    float al0 = expf(m0 - mn0), al1 = expf(m1 - mn1);
    float ls0 = 0.f, ls1 = 0.f;
#pragma unroll
    for (int sj = 0; sj < 8; sj++) {
      p0[sj] = expf(p0[sj] - mn0); ls0 += p0[sj];
      p1[sj] = expf(p1[sj] - mn1); ls1 += p1[sj];
    }
#pragma unroll
    for (int off = 1; off < 8; off <<= 1) {
      ls0 += __shfl_xor(ls0, off);
      ls1 += __shfl_xor(ls1, off);
    }
    l0 = l0 * al0 + ls0;
    l1 = l1 * al1 + ls1;
    m0 = mn0; m1 = mn1;
#pragma unroll
    for (int d = 0; d < 8; d++) { O0[d] *= al0; O1[d] *= al1; }

    // PV: broadcast P via shfl (P[row r][s=sj*8+cc] lives in lane (lane&56)|cc)
#pragma unroll
    for (int sj = 0; sj < 8; sj++) {
#pragma unroll
      for (int cc = 0; cc < 8; cc++) {
        int src = (tid & 56) | cc;
        float pa = __shfl(p0[sj], src);
        float pb = __shfl(p1[sj], src);
        int s2 = sj * 8 + cc;
        const float4* vv = (const float4*)&Vs[s2][c * 8];
        float4 va = vv[0], vb = vv[1];
        O0[0] += pa * va.x; O0[1] += pa * va.y; O0[2] += pa * va.z; O0[3] += pa * va.w;
        O0[4] += pa * vb.x; O0[5] += pa * vb.y; O0[6] += pa * vb.z; O0[7] += pa * vb.w;
        O1[0] += pb * va.x; O1[1] += pb * va.y; O1[2] += pb * va.z; O1[3] += pb * va.w;
        O1[4] += pb * vb.x; O1[5] += pb * vb.y; O1[6] += pb * vb.z; O1[7] += pb * vb.w;
      }
    }
  }

  float inv0 = 1.f / l0, inv1 = 1.f / l1;
  int t0 = rb + r, t1 = rb + r + 32;
  float* o0 = ctx + ((size_t)(t0 * B_ + b)) * D_ + h * HD_ + c * 8;
  float* o1 = ctx + ((size_t)(t1 * B_ + b)) * D_ + h * HD_ + c * 8;
#pragma unroll
  for (int d = 0; d < 8; d++) {
    o0[d] = O0[d] * inv0;
    o1[d] = O1[d] * inv1;
  }
}

// ---------------------------------------------------------------------------
// Fused residual + LayerNorm: out = LN(A*alpha + R) * g + b. One row / block.
// ---------------------------------------------------------------------------
__global__ __launch_bounds__(256) void ln_fused(
    const float* __restrict__ A, const float* __restrict__ Rr,
    const float* __restrict__ g, const float* __restrict__ be,
    float* __restrict__ out, float alpha) {
  int row = blockIdx.x, tid = threadIdx.x;
  const float* a = A + (size_t)row * D_;
  const float* rr = Rr + (size_t)row * D_;
  float v[3];
  float s = 0.f, s2 = 0.f;
#pragma unroll
  for (int j = 0; j < 3; j++) {
    int col = tid + j * 256;
    float x = a[col] * alpha + rr[col];
    v[j] = x; s += x; s2 += x * x;
  }
  __shared__ float red[8];
#pragma unroll
  for (int off = 32; off >= 1; off >>= 1) {
    s  += __shfl_down(s, off);
    s2 += __shfl_down(s2, off);
  }
  int wv = tid >> 6;
  if ((tid & 63) == 0) { red[wv] = s; red[4 + wv] = s2; }
  __syncthreads();
  s  = red[0] + red[1] + red[2] + red[3];
  s2 = red[4] + red[5] + red[6] + red[7];
  float mu  = s * (1.f / 768.f);
  float var = s2 * (1.f / 768.f) - mu * mu;
  float inv = rsqrtf(var + 1e-5f);
#pragma unroll
  for (int j = 0; j < 3; j++) {
    int col = tid + j * 256;
    out[(size_t)row * D_ + col] = (v[j] - mu) * inv * g[col] + be[col];
  }
}

// ---------------------------------------------------------------------------
__global__ __launch_bounds__(256) void copy_f4(
    const float4* __restrict__ src, float4* __restrict__ dst, int n4) {
  int i = blockIdx.x * 256 + threadIdx.x;
  if (i < n4) dst[i] = src[i];
}

// ---------------------------------------------------------------------------
extern "C" void kernel_launch(void* const* d_in, const int* in_sizes, int n_in,
                              void* d_out, int out_size, void* d_ws, size_t ws_size,
                              hipStream_t stream) {
  const float* states = (const float*)d_in[0];
  const float* pbias  = (const float*)d_in[1];
  const float* Wq = (const float*)d_in[2];
  const float* bq = (const float*)d_in[3];
  const float* Wk = (const float*)d_in[4];
  const float* bk = (const float*)d_in[5];
  const float* Wv = (const float*)d_in[6];
  const float* bv = (const float*)d_in[7];
  const float* Wo = (const float*)d_in[8];
  const float* bo = (const float*)d_in[9];
  const float* grep_w = (const float*)d_in[10];
  const float* grep_b = (const float*)d_in[11];
  const float* grep_a = (const float*)d_in[12];
  const float* ln1_g = (const float*)d_in[13];
  const float* ln1_b = (const float*)d_in[14];
  const float* W1 = (const float*)d_in[15];
  const float* b1 = (const float*)d_in[16];
  const float* W2 = (const float*)d_in[17];
  const float* b2 = (const float*)d_in[18];
  const float* ln2_g = (const float*)d_in[19];
  const float* ln2_b = (const float*)d_in[20];

  float* ws = (float*)d_ws;
  float* qh  = ws;                 // 48*1024*64 = 3,145,728
  float* kh  = ws + 3145728;       // 3,145,728
  float* vh  = ws + 6291456;       // 3,145,728
  float* msc = ws + 9437184;       // 49,152
  float* ctx = ws + 9486336;       // 3,145,728
  float* h1  = ws + 12632064;      // 12,582,912  (ends 25,214,976 floats ~101MB)
  float* attn = qh;                // reuse: qh dead after flash_attn+gate
  float* x    = kh;                // reuse: kh dead after flash_attn
  float* h2   = vh;                // reuse: vh dead after flash_attn
  float* outp = (float*)d_out;

  dim3 blk(256);
  // QKV projections (head-major scatter; q scaled by 0.125/32 = 1/256)
  gemm_xwt<<<dim3(12, 64), blk, 0, stream>>>(states, Wq, bq, qh, 768, 768, MODE_HEAD, 1.f / 256.f);
  gemm_xwt<<<dim3(12, 64), blk, 0, stream>>>(states, Wk, bk, kh, 768, 768, MODE_HEAD, 1.f);
  gemm_xwt<<<dim3(12, 64), blk, 0, stream>>>(states, Wv, bv, vh, 768, 768, MODE_HEAD, 1.f);
  // gates -> per-(head,row) mask scale
  gate_kernel<<<192, blk, 0, stream>>>(qh, grep_w, grep_b, grep_a, msc);
  // fused attention -> ctx in token-major (T,B,D)
  flash_attn<<<dim3(16, 48), blk, 0, stream>>>(qh, kh, vh, pbias, msc, ctx);
  // output projection
  gemm_xwt<<<dim3(12, 64), blk, 0, stream>>>(ctx, Wo, bo, attn, 768, 768, MODE_PLAIN, 1.f);
  // x = LN(states*ALPHA + attn)
  ln_fused<<<4096, blk, 0, stream>>>(states, attn, ln1_g, ln1_b, x, ALPHA_);
  // FFN
  gemm_xwt<<<dim3(48, 64), blk, 0, stream>>>(x, W1, b1, h1, 768, 3072, MODE_GELU, 1.f);
  gemm_xwt<<<dim3(12, 64), blk, 0, stream>>>(h1, W2, b2, h2, 3072, 768, MODE_PLAIN, 1.f);
  // out = LN(h2 + x*ALPHA)
  ln_fused<<<4096, blk, 0, stream>>>(x, h2, ln2_g, ln2_b, outp, ALPHA_);
  // second output: pass-through positional_bias
  copy_f4<<<49152, blk, 0, stream>>>((const float4*)pbias, (float4*)(outp + 3145728), 12582912);
}

// Round 2
// 968.410 us; speedup vs baseline: 1.6457x; 1.6457x over previous
//
#include <hip/hip_runtime.h>
#include <hip/hip_bf16.h>

// Problem constants
#define T_    1024
#define B_    4
#define D_    768
#define H_    12
#define HD_   64
#define FF_   3072

typedef __bf16 bf16;
typedef __bf16 v8bf __attribute__((ext_vector_type(8)));
typedef __bf16 v4bf __attribute__((ext_vector_type(4)));
typedef float  v4f  __attribute__((ext_vector_type(4)));

#define AS1 __attribute__((address_space(1)))
#define AS3 __attribute__((address_space(3)))
// async global->LDS, 16B per lane, deposit = wave-uniform base + lane*16
#define GLOAD_LDS(g, l) __builtin_amdgcn_global_load_lds((AS1 void*)(g), (AS3 void*)(l), 16, 0, 0)

static const float ALPHA_ = 2.2133638394006434f; // 24^0.25

#define MODE_PLAIN 0
#define MODE_GELU  1

// ---------------------------------------------------------------------------
// cast fp32 -> bf16, 4 elems/thread
// ---------------------------------------------------------------------------
__global__ __launch_bounds__(256) void cast_bf(
    const float4* __restrict__ in, v4bf* __restrict__ out, int n4) {
  int i = blockIdx.x * 256 + threadIdx.x;
  if (i < n4) {
    float4 v = in[i];
    v4bf o;
    o[0] = (bf16)v.x; o[1] = (bf16)v.y; o[2] = (bf16)v.z; o[3] = (bf16)v.w;
    out[i] = o;
  }
}

// ---------------------------------------------------------------------------
// MFMA GEMM core: Out(128x128 tile) = X(N x K) @ W(M x K)^T.
// LDS is stored in MFMA-fragment order: 8 blocks of 1024B per tile; block g
// holds rows 16g..16g+15; within a block, lane l's 16B chunk is exactly the
// fragment lane l reads (row = l&15, k-bytes = (l>>4)*16). So global_load_lds
// (wave-uniform base + lane*16) deposits fragments in place, and the compute
// ds_read_b128 at base + lane*16 is contiguous (conflict-free).
// 256 threads = 4 waves in a 2x2 grid, each wave owns a 64x64 sub-tile.
// ---------------------------------------------------------------------------
__device__ __forceinline__ void gemm_core(
    const bf16* __restrict__ X, const bf16* __restrict__ W, int K,
    int row0, int col0, bf16* As, bf16* Bs, v4f (&acc)[4][4]) {
  const int tid  = threadIdx.x;
  const int lane = tid & 63;
  const int w    = tid >> 6;        // wave 0..3
  const int wm   = w >> 1, wn = w & 1;
  const int lr   = lane & 15;       // row within 16-row group
  const int lq   = lane >> 4;       // k-quad 0..3 (8 bf16 = 16B each)

  const bf16* xg0 = X + (size_t)(row0 + 16 * w       + lr) * K + lq * 8;
  const bf16* xg1 = X + (size_t)(row0 + 16 * (w + 4) + lr) * K + lq * 8;
  const bf16* wg0 = W + (size_t)(col0 + 16 * w       + lr) * K + lq * 8;
  const bf16* wg1 = W + (size_t)(col0 + 16 * (w + 4) + lr) * K + lq * 8;
  char* AsB = (char*)As;
  char* BsB = (char*)Bs;

  for (int k0 = 0; k0 < K; k0 += 32) {
    __syncthreads();
    GLOAD_LDS(xg0 + k0, AsB + w * 1024);
    GLOAD_LDS(xg1 + k0, AsB + (w + 4) * 1024);
    GLOAD_LDS(wg0 + k0, BsB + w * 1024);
    GLOAD_LDS(wg1 + k0, BsB + (w + 4) * 1024);
    __syncthreads();

    v8bf af[4], bw[4];
#pragma unroll
    for (int mi = 0; mi < 4; mi++)
      af[mi] = *(const v8bf*)(AsB + (wm * 4 + mi) * 1024 + lane * 16);
#pragma unroll
    for (int ni = 0; ni < 4; ni++)
      bw[ni] = *(const v8bf*)(BsB + (wn * 4 + ni) * 1024 + lane * 16);
#pragma unroll
    for (int mi = 0; mi < 4; mi++)
#pragma unroll
      for (int ni = 0; ni < 4; ni++)
        acc[mi][ni] = __builtin_amdgcn_mfma_f32_16x16x32_bf16(
            af[mi], bw[ni], acc[mi][ni], 0, 0, 0);
  }
}

// ---------------------------------------------------------------------------
// Generic MFMA GEMM: out = X @ W^T + bias, PLAIN(f32) or GELU(bf16) epilogue.
// Grid (M/128, N/128), 256 threads.
// ---------------------------------------------------------------------------
__global__ __launch_bounds__(256) void gemm_mfma(
    const bf16* __restrict__ X, const bf16* __restrict__ W,
    const float* __restrict__ bias, void* __restrict__ out,
    int K, int M, int mode) {
  __shared__ __align__(16) bf16 As[128 * 32];
  __shared__ __align__(16) bf16 Bs[128 * 32];
  const int row0 = blockIdx.y * 128, col0 = blockIdx.x * 128;

  v4f acc[4][4];
  v4f z4 = {0.f, 0.f, 0.f, 0.f};
#pragma unroll
  for (int mi = 0; mi < 4; mi++)
#pragma unroll
    for (int ni = 0; ni < 4; ni++) acc[mi][ni] = z4;

  gemm_core(X, W, K, row0, col0, As, Bs, acc);

  // epilogue: C/D layout col = lane&15, row = (lane>>4)*4 + reg
  const int lane = threadIdx.x & 63;
  const int w = threadIdx.x >> 6, wm = w >> 1, wn = w & 1;
  const int lr = lane & 15, lq = lane >> 4;
#pragma unroll
  for (int ni = 0; ni < 4; ni++) {
    int col = col0 + wn * 64 + ni * 16 + lr;
    float bv = bias[col];
#pragma unroll
    for (int mi = 0; mi < 4; mi++) {
#pragma unroll
      for (int i = 0; i < 4; i++) {
        int row = row0 + wm * 64 + mi * 16 + lq * 4 + i;
        float v = acc[mi][ni][i] + bv;
        if (mode == MODE_GELU) {
          v = 0.5f * v * (1.f + erff(v * 0.70710678118654752f));
          ((bf16*)out)[(size_t)row * M + col] = (bf16)v;
        } else {
          ((float*)out)[(size_t)row * M + col] = v;
        }
      }
    }
  }
}

// ---------------------------------------------------------------------------
// Fused QKV MFMA GEMM with head-major scatter epilogue.
// Grid (18, 32): blockIdx.x/6 selects q/k/v, %6 is the 128-col tile.
// q is scaled by 0.125/32 = 1/256 after bias.
// ---------------------------------------------------------------------------
__global__ __launch_bounds__(256) void qkv_mfma(
    const bf16* __restrict__ Xb,
    const bf16* __restrict__ Wqb, const bf16* __restrict__ Wkb,
    const bf16* __restrict__ Wvb,
    const float* __restrict__ bq, const float* __restrict__ bk,
    const float* __restrict__ bv,
    float* __restrict__ qh, float* __restrict__ kh, float* __restrict__ vh) {
  __shared__ __align__(16) bf16 As[128 * 32];
  __shared__ __align__(16) bf16 Bs[128 * 32];
  const int third = blockIdx.x / 6;
  const int xt    = blockIdx.x % 6;
  const bf16*  W    = third == 0 ? Wqb : (third == 1 ? Wkb : Wvb);
  const float* bias = third == 0 ? bq  : (third == 1 ? bk  : bv);
  float*       outp = third == 0 ? qh  : (third == 1 ? kh  : vh);
  const float scale = third == 0 ? (0.125f / 32.f) : 1.f;
  const int row0 = blockIdx.y * 128, col0 = xt * 128;

  v4f acc[4][4];
  v4f z4 = {0.f, 0.f, 0.f, 0.f};
#pragma unroll
  for (int mi = 0; mi < 4; mi++)
#pragma unroll
    for (int ni = 0; ni < 4; ni++) acc[mi][ni] = z4;

  gemm_core(Xb, W, D_, row0, col0, As, Bs, acc);

  const int lane = threadIdx.x & 63;
  const int w = threadIdx.x >> 6, wm = w >> 1, wn = w & 1;
  const int lr = lane & 15, lq = lane >> 4;
#pragma unroll
  for (int ni = 0; ni < 4; ni++) {
    int col = col0 + wn * 64 + ni * 16 + lr;
    float bvv = bias[col];
    int h = col >> 6, hd = col & 63;
#pragma unroll
    for (int mi = 0; mi < 4; mi++) {
#pragma unroll
      for (int i = 0; i < 4; i++) {
        int row = row0 + wm * 64 + mi * 16 + lq * 4 + i; // token = t*B + bb
        int t = row >> 2, bb = row & 3;
        float v = (acc[mi][ni][i] + bvv) * scale;
        outp[(((size_t)(bb * H_ + h)) * T_ + t) * HD_ + hd] = v;
      }
    }
  }
}

// ---------------------------------------------------------------------------
// Gate kernel: mask_scale[n][t] = ga*(gb*grep_a[h]-1)+2 from q_full = q*256
// ---------------------------------------------------------------------------
__global__ __launch_bounds__(256) void gate_kernel(
    const float* __restrict__ qh, const float* __restrict__ grep_w,
    const float* __restrict__ grep_b, const float* __restrict__ grep_a,
    float* __restrict__ msc) {
  int gid = blockIdx.x * 256 + threadIdx.x;   // n*1024 + t
  int n = gid >> 10;
  int h = n % H_;
  const float* q = qh + (size_t)gid * HD_;
  float z[8];
#pragma unroll
  for (int o = 0; o < 8; o++) z[o] = grep_b[o];
  for (int k = 0; k < 64; k++) {
    float qv = q[k] * 256.f;
#pragma unroll
    for (int o = 0; o < 8; o++) z[o] += qv * grep_w[o * 64 + k];
  }
  float s0 = z[0] + z[1] + z[2] + z[3];
  float s1 = z[4] + z[5] + z[6] + z[7];
  float ga = 1.f / (1.f + expf(-s0));
  float gb = 1.f / (1.f + expf(-s1));
  msc[gid] = ga * (gb * grep_a[h] - 1.f) + 2.f;
}

// ---------------------------------------------------------------------------
// Flash attention (fp32 compute), ctx written as bf16 (feeds Wo MFMA GEMM).
// ---------------------------------------------------------------------------
__global__ __launch_bounds__(256) void flash_attn(
    const float* __restrict__ Q, const float* __restrict__ Kh,
    const float* __restrict__ Vh, const float* __restrict__ bias,
    const float* __restrict__ msc, bf16* __restrict__ ctx) {
  __shared__ float Qs[64][68];
  __shared__ float Ks[64][68];
  __shared__ float Vs[64][68];
  int n  = blockIdx.y;
  int rb = blockIdx.x * 64;
  int tid = threadIdx.x;
  int r = tid >> 3;   // 0..31
  int c = tid & 7;    // 0..7
  int b = n / H_, h = n % H_;
  const float* Qp = Q  + (size_t)n * T_ * HD_;
  const float* Kp = Kh + (size_t)n * T_ * HD_;
  const float* Vp = Vh + (size_t)n * T_ * HD_;

  {
    int qr = tid >> 2, qs = (tid & 3) * 16;
    const float4* src = (const float4*)(Qp + (size_t)(rb + qr) * HD_ + qs);
    float4* dst = (float4*)&Qs[qr][qs];
    dst[0] = src[0]; dst[1] = src[1]; dst[2] = src[2]; dst[3] = src[3];
  }

  float m0 = -1e30f, m1 = -1e30f, l0 = 0.f, l1 = 0.f;
  float O0[8], O1[8];
#pragma unroll
  for (int d = 0; d < 8; d++) { O0[d] = 0.f; O1[d] = 0.f; }
  float ms0 = msc[n * T_ + rb + r];
  float ms1 = msc[n * T_ + rb + r + 32];
  const float* br0 = bias + ((size_t)n * T_ + rb + r) * T_;
  const float* br1 = bias + ((size_t)n * T_ + rb + r + 32) * T_;

  for (int cb = 0; cb < T_; cb += 64) {
    __syncthreads();
    {
      int kr = tid >> 2, ks = (tid & 3) * 16;
      const float4* sk = (const float4*)(Kp + (size_t)(cb + kr) * HD_ + ks);
      const float4* sv = (const float4*)(Vp + (size_t)(cb + kr) * HD_ + ks);
      float4* dk = (float4*)&Ks[kr][ks];
      float4* dv = (float4*)&Vs[kr][ks];
      dk[0] = sk[0]; dk[1] = sk[1]; dk[2] = sk[2]; dk[3] = sk[3];
      dv[0] = sv[0]; dv[1] = sv[1]; dv[2] = sv[2]; dv[3] = sv[3];
    }
    __syncthreads();

    float p0[8], p1[8];
#pragma unroll
    for (int sj = 0; sj < 8; sj++) { p0[sj] = 0.f; p1[sj] = 0.f; }
    for (int k4 = 0; k4 < 64; k4 += 4) {
      float4 qa = *(const float4*)&Qs[r][k4];
      float4 qb = *(const float4*)&Qs[r + 32][k4];
#pragma unroll
      for (int sj = 0; sj < 8; sj++) {
        int s = sj * 8 + c;
        float4 kv = *(const float4*)&Ks[s][k4];
        p0[sj] += qa.x * kv.x + qa.y * kv.y + qa.z * kv.z + qa.w * kv.w;
        p1[sj] += qb.x * kv.x + qb.y * kv.y + qb.z * kv.z + qb.w * kv.w;
      }
    }
    float tmax0 = -1e30f, tmax1 = -1e30f;
#pragma unroll
    for (int sj = 0; sj < 8; sj++) {
      int s = sj * 8 + c;
      float bv0 = br0[cb + s];
      float bv1 = br1[cb + s];
      p0[sj] = p0[sj] * 32.f + ms0 * bv0;
      p1[sj] = p1[sj] * 32.f + ms1 * bv1;
      tmax0 = fmaxf(tmax0, p0[sj]);
      tmax1 = fmaxf(tmax1, p1[sj]);
    }
#pragma unroll
    for (int off = 1; off < 8; off <<= 1) {
      tmax0 = fmaxf(tmax0, __shfl_xor(tmax0, off));
      tmax1 = fmaxf(tmax1, __shfl_xor(tmax1, off));
    }
    float mn0 = fmaxf(m0, tmax0), mn1 = fmaxf(m1, tmax1);
    float al0 = expf(m0 - mn0), al1 = expf(m1 - mn1);
    float ls0 = 0.f, ls1 = 0.f;
#pragma unroll
    for (int sj = 0; sj < 8; sj++) {
      p0[sj] = expf(p0[sj] - mn0); ls0 += p0[sj];
      p1[sj] = expf(p1[sj] - mn1); ls1 += p1[sj];
    }
#pragma unroll
    for (int off = 1; off < 8; off <<= 1) {
      ls0 += __shfl_xor(ls0, off);
      ls1 += __shfl_xor(ls1, off);
    }
    l0 = l0 * al0 + ls0;
    l1 = l1 * al1 + ls1;
    m0 = mn0; m1 = mn1;
#pragma unroll
    for (int d = 0; d < 8; d++) { O0[d] *= al0; O1[d] *= al1; }

#pragma unroll
    for (int sj = 0; sj < 8; sj++) {
#pragma unroll
      for (int cc = 0; cc < 8; cc++) {
        int src = (tid & 56) | cc;
        float pa = __shfl(p0[sj], src);
        float pb = __shfl(p1[sj], src);
        int s2 = sj * 8 + cc;
        const float4* vv = (const float4*)&Vs[s2][c * 8];
        float4 va = vv[0], vb = vv[1];
        O0[0] += pa * va.x; O0[1] += pa * va.y; O0[2] += pa * va.z; O0[3] += pa * va.w;
        O0[4] += pa * vb.x; O0[5] += pa * vb.y; O0[6] += pa * vb.z; O0[7] += pa * vb.w;
        O1[0] += pb * va.x; O1[1] += pb * va.y; O1[2] += pb * va.z; O1[3] += pb * va.w;
        O1[4] += pb * vb.x; O1[5] += pb * vb.y; O1[6] += pb * vb.z; O1[7] += pb * vb.w;
      }
    }
  }

  float inv0 = 1.f / l0, inv1 = 1.f / l1;
  int t0 = rb + r, t1 = rb + r + 32;
  bf16* o0 = ctx + ((size_t)(t0 * B_ + b)) * D_ + h * HD_ + c * 8;
  bf16* o1 = ctx + ((size_t)(t1 * B_ + b)) * D_ + h * HD_ + c * 8;
#pragma unroll
  for (int d = 0; d < 8; d++) {
    o0[d] = (bf16)(O0[d] * inv0);
    o1[d] = (bf16)(O1[d] * inv1);
  }
}

// ---------------------------------------------------------------------------
// Fused residual + LayerNorm: out = LN(A*alpha + R)*g + b, optional bf16 copy.
// ---------------------------------------------------------------------------
__global__ __launch_bounds__(256) void ln_fused(
    const float* __restrict__ A, const float* __restrict__ Rr,
    const float* __restrict__ g, const float* __restrict__ be,
    float* __restrict__ out, bf16* __restrict__ outb, float alpha) {
  int row = blockIdx.x, tid = threadIdx.x;
  const float* a = A + (size_t)row * D_;
  const float* rr = Rr + (size_t)row * D_;
  float v[3];
  float s = 0.f, s2 = 0.f;
#pragma unroll
  for (int j = 0; j < 3; j++) {
    int col = tid + j * 256;
    float x = a[col] * alpha + rr[col];
    v[j] = x; s += x; s2 += x * x;
  }
  __shared__ float red[8];
#pragma unroll
  for (int off = 32; off >= 1; off >>= 1) {
    s  += __shfl_down(s, off);
    s2 += __shfl_down(s2, off);
  }
  int wv = tid >> 6;
  if ((tid & 63) == 0) { red[wv] = s; red[4 + wv] = s2; }
  __syncthreads();
  s  = red[0] + red[1] + red[2] + red[3];
  s2 = red[4] + red[5] + red[6] + red[7];
  float mu  = s * (1.f / 768.f);
  float var = s2 * (1.f / 768.f) - mu * mu;
  float inv = rsqrtf(var + 1e-5f);
#pragma unroll
  for (int j = 0; j < 3; j++) {
    int col = tid + j * 256;
    float y = (v[j] - mu) * inv * g[col] + be[col];
    out[(size_t)row * D_ + col] = y;
    if (outb) outb[(size_t)row * D_ + col] = (bf16)y;
  }
}

// ---------------------------------------------------------------------------
__global__ __launch_bounds__(256) void copy_f4(
    const float4* __restrict__ src, float4* __restrict__ dst, int n4) {
  int i = blockIdx.x * 256 + threadIdx.x;
  if (i < n4) dst[i] = src[i];
}

// ---------------------------------------------------------------------------
extern "C" void kernel_launch(void* const* d_in, const int* in_sizes, int n_in,
                              void* d_out, int out_size, void* d_ws, size_t ws_size,
                              hipStream_t stream) {
  const float* states = (const float*)d_in[0];
  const float* pbias  = (const float*)d_in[1];
  const float* Wq = (const float*)d_in[2];
  const float* bq = (const float*)d_in[3];
  const float* Wk = (const float*)d_in[4];
  const float* bk = (const float*)d_in[5];
  const float* Wv = (const float*)d_in[6];
  const float* bv = (const float*)d_in[7];
  const float* Wo = (const float*)d_in[8];
  const float* bo = (const float*)d_in[9];
  const float* grep_w = (const float*)d_in[10];
  const float* grep_b = (const float*)d_in[11];
  const float* grep_a = (const float*)d_in[12];
  const float* ln1_g = (const float*)d_in[13];
  const float* ln1_b = (const float*)d_in[14];
  const float* W1 = (const float*)d_in[15];
  const float* b1 = (const float*)d_in[16];
  const float* W2 = (const float*)d_in[17];
  const float* b2 = (const float*)d_in[18];
  const float* ln2_g = (const float*)d_in[19];
  const float* ln2_b = (const float*)d_in[20];

  float* ws = (float*)d_ws;
  float* qh   = ws;                  // 3,145,728 f32
  float* kh   = ws + 3145728;        // 3,145,728
  float* vh   = ws + 6291456;        // 3,145,728
  float* msc  = ws + 9437184;        //    49,152
  bf16* states_bf = (bf16*)(ws + 9486336);   // 3,145,728 bf16
  bf16* ctx_bf    = (bf16*)(ws + 11059200);  // 3,145,728 bf16
  bf16* x_bf      = (bf16*)(ws + 12632064);  // 3,145,728 bf16
  bf16* h1_bf     = (bf16*)(ws + 14204928);  // 12,582,912 bf16
  bf16* wq_bf     = (bf16*)(ws + 20496384);  // 589,824 bf16
  bf16* wk_bf     = (bf16*)(ws + 20791296);
  bf16* wv_bf     = (bf16*)(ws + 21086208);
  bf16* wo_bf     = (bf16*)(ws + 21381120);
  bf16* w1_bf     = (bf16*)(ws + 21676032);  // 2,359,296 bf16
  bf16* w2_bf     = (bf16*)(ws + 22855680);  // ends at 24,035,328 f32 (~96 MB)
  float* attn = qh;   // reuse: qh dead after gate+flash
  float* x    = kh;   // reuse: kh dead after flash
  float* h2   = vh;   // reuse: vh dead after flash
  float* outp = (float*)d_out;

  dim3 blk(256);
  // fp32 -> bf16 casts
  cast_bf<<<3072, blk, 0, stream>>>((const float4*)states, (v4bf*)states_bf, 786432);
  cast_bf<<<576,  blk, 0, stream>>>((const float4*)Wq, (v4bf*)wq_bf, 147456);
  cast_bf<<<576,  blk, 0, stream>>>((const float4*)Wk, (v4bf*)wk_bf, 147456);
  cast_bf<<<576,  blk, 0, stream>>>((const float4*)Wv, (v4bf*)wv_bf, 147456);
  cast_bf<<<576,  blk, 0, stream>>>((const float4*)Wo, (v4bf*)wo_bf, 147456);
  cast_bf<<<2304, blk, 0, stream>>>((const float4*)W1, (v4bf*)w1_bf, 589824);
  cast_bf<<<2304, blk, 0, stream>>>((const float4*)W2, (v4bf*)w2_bf, 589824);

  // fused QKV (MFMA), head-major outputs, q scaled by 1/256
  qkv_mfma<<<dim3(18, 32), blk, 0, stream>>>(states_bf, wq_bf, wk_bf, wv_bf,
                                             bq, bk, bv, qh, kh, vh);
  // gates -> per-(head,row) mask scale
  gate_kernel<<<192, blk, 0, stream>>>(qh, grep_w, grep_b, grep_a, msc);
  // fused attention -> ctx (bf16, token-major (T,B,D))
  flash_attn<<<dim3(16, 48), blk, 0, stream>>>(qh, kh, vh, pbias, msc, ctx_bf);
  // output projection (MFMA)
  gemm_mfma<<<dim3(6, 32), blk, 0, stream>>>(ctx_bf, wo_bf, bo, attn, 768, 768, MODE_PLAIN);
  // x = LN(states*ALPHA + attn), also emit bf16 copy for FFN
  ln_fused<<<4096, blk, 0, stream>>>(states, attn, ln1_g, ln1_b, x, x_bf, ALPHA_);
  // FFN (MFMA): GELU epilogue writes bf16 h1 directly
  gemm_mfma<<<dim3(24, 32), blk, 0, stream>>>(x_bf, w1_bf, b1, h1_bf, 768, 3072, MODE_GELU);
  gemm_mfma<<<dim3(6, 32), blk, 0, stream>>>(h1_bf, w2_bf, b2, h2, 3072, 768, MODE_PLAIN);
  // out = LN(h2 + x*ALPHA)
  ln_fused<<<4096, blk, 0, stream>>>(x, h2, ln2_g, ln2_b, outp, (bf16*)nullptr, ALPHA_);
  // second output: pass-through positional_bias
  copy_f4<<<49152, blk, 0, stream>>>((const float4*)pbias, (float4*)(outp + 3145728), 12582912);
}